// Round 5
// baseline (176.514 us; speedup 1.0000x reference)
//
#include <hip/hip_runtime.h>
#include <stdint.h>
#include <math.h>

typedef __bf16 bf16x8 __attribute__((ext_vector_type(8)));
typedef float f32x4 __attribute__((ext_vector_type(4)));
typedef unsigned short u16x8 __attribute__((ext_vector_type(8)));

__device__ __forceinline__ unsigned short f32_to_bf16_rne(float f) {
    unsigned u = __builtin_bit_cast(unsigned, f);
    u += 0x7fffu + ((u >> 16) & 1u);
    return (unsigned short)(u >> 16);
}

// ---------------------------------------------------------------------------
// int8 symmetric group-wise fake-quant, group 128 along contiguous axis.
// 32 lanes per group, one float4 per lane. Output = bf16(q*scale).
// At HBM BW roofline — unchanged.
// ---------------------------------------------------------------------------
__global__ __launch_bounds__(256) void quant_fake_int8_kernel(
    const float* __restrict__ in, unsigned short* __restrict__ out,
    long long n) {
    long long t = (long long)blockIdx.x * 256 + threadIdx.x;
    long long base = t * 4;
    if (base >= n) return;
    const float4 v = *reinterpret_cast<const float4*>(in + base);
    float m = fmaxf(fmaxf(fabsf(v.x), fabsf(v.y)),
                    fmaxf(fabsf(v.z), fabsf(v.w)));
#pragma unroll
    for (int off = 1; off <= 16; off <<= 1)
        m = fmaxf(m, __shfl_xor(m, off, 64));
    const float scale = fmaxf(m / 127.0f, 1e-8f);
    const float d0 = fminf(fmaxf(rintf(v.x / scale), -128.0f), 127.0f) * scale;
    const float d1 = fminf(fmaxf(rintf(v.y / scale), -128.0f), 127.0f) * scale;
    const float d2 = fminf(fmaxf(rintf(v.z / scale), -128.0f), 127.0f) * scale;
    const float d3 = fminf(fmaxf(rintf(v.w / scale), -128.0f), 127.0f) * scale;
    ushort4 o;
    o.x = f32_to_bf16_rne(d0);
    o.y = f32_to_bf16_rne(d1);
    o.z = f32_to_bf16_rne(d2);
    o.w = f32_to_bf16_rne(d3);
    *reinterpret_cast<ushort4*>(out + base) = o;
}

// ---------------------------------------------------------------------------
// 256x256 bf16 GEMM, BK=32, ring-4 LDS, depth-3 prefetch, counted vmcnt,
// and REGISTER-PIPELINED fragments: body kt runs 32 MFMA on tile kt's frags
// while issuing ds_reads for tile kt+1 and the global stage of tile kt+3.
// ONE barrier per K-tile.
//
// Safety ledger:
//  * vmcnt: at body-kt top, outstanding = kt+1(4) + kt+2(4) = 8 ->
//    vmcnt(4) drains kt+1 exactly (stage of kt+3 issues after the barrier).
//    Tail: kt+2>=NT -> vmcnt(0); kt+1>=NT -> none.
//  * WAR on ring slots: stage(kt+3) in body kt writes slot (kt-1)&3, whose
//    frags were ds_read in body kt-2 and lgkm-consumed by MFMAs in body
//    kt-1. Barrier kt releases only after ALL waves finished body kt-1,
//    so every read of that slot retired before any wave's stage -> safe.
//  * A-hi JIT reads at body-kt top (before the barrier) target slot kt&3,
//    visible since barrier kt-1; the conflicting overwrite (stage kt+4,
//    body kt+1) happens after barrier kt+1, which requires this body's
//    MFMAs (the consumers) to have retired the reads -> safe.
// Swizzle (64B rows): colbyte ^ (((row>>1)&3)<<4), pre-swizzled global
// source + swizzled ds_read address (both-sides). Verified: conflicts = 0.
// ---------------------------------------------------------------------------
#define BM 256
#define BN 256
#define BKT 32

__device__ __forceinline__ void stage32(const unsigned short* __restrict__ G,
                                        unsigned short* L, int tid,
                                        int baseRow, int K, int k0) {
    // tile = [256][32] bf16, 64 B/row. 2 loads x 512 thr x 16 B = 16 KB.
    const int r = tid >> 2;                                        // 0..127
    const int scb = (((tid & 3) << 4) ^ (((r >> 1) & 3) << 4)) >> 1;
#pragma unroll
    for (int i = 0; i < 2; ++i) {
        __builtin_amdgcn_global_load_lds(
            (const __attribute__((address_space(1))) void*)(
                G + (size_t)(baseRow + i * 128 + r) * K + k0 + scb),
            (__attribute__((address_space(3))) void*)(
                L + i * 4096 + (tid >> 6) * 512),
            16, 0, 0);
    }
}

#define LDF32(BASE, ROW)                                         \
    __builtin_bit_cast(bf16x8, *reinterpret_cast<const u16x8*>(  \
                                   (BASE) + (((ROW) << 5) + coe)))

#define MFMA(a, bb, c) __builtin_amdgcn_mfma_f32_16x16x32_bf16(a, bb, c, 0, 0, 0)

__global__ __launch_bounds__(512, 2) void gemm_bf16_pipe(
    const unsigned short* __restrict__ A,  // [M][K] bf16 bits
    const unsigned short* __restrict__ B,  // [N][K] bf16 bits
    float* __restrict__ C,                 // [M][N]
    int M, int N, int K) {
    __shared__ __align__(16) unsigned short lds[4][2][BM * BKT];  // 128 KB

    const int tid = threadIdx.x;
    const int lane = tid & 63;
    const int wid = tid >> 6;
    const int wr = wid >> 2;  // 0..1  (M half)
    const int wc = wid & 3;   // 0..3  (N quarter)
    const int l15 = lane & 15;
    const int lh = lane >> 4;  // 0..3 = k-slot (16B each)
    const int coe = (((lh << 4) ^ (((l15 >> 1) & 3) << 4)) >> 1);
    const int ra = wr * 128 + l15;  // + m*16
    const int rb = wc * 64 + l15;   // + n*16

    // XCD-chunked bijective remap over 512 blocks (512 % 8 == 0).
    const int id = (blockIdx.x & 7) * 64 + (blockIdx.x >> 3);
    const int tileN = (id & 7) * BN;
    const int tileM = (id >> 3) * BM;

    const int NT = K >> 5;  // 64

    f32x4 acc[8][4] = {};
    bf16x8 falo[2][4];  // A rows m0..3, double-buffered by kt parity
    bf16x8 fb4[2][4];   // B rows n0..3, double-buffered by kt parity

    // prologue: stage K-tiles 0,1,2 (12 loads)
    stage32(A, &lds[0][0][0], tid, tileM, K, 0);
    stage32(B, &lds[0][1][0], tid, tileN, K, 0);
    stage32(A, &lds[1][0][0], tid, tileM, K, 32);
    stage32(B, &lds[1][1][0], tid, tileN, K, 32);
    stage32(A, &lds[2][0][0], tid, tileM, K, 64);
    stage32(B, &lds[2][1][0], tid, tileN, K, 64);
    asm volatile("s_waitcnt vmcnt(8)" ::: "memory");  // tile 0 arrived
    __builtin_amdgcn_s_barrier();
    __builtin_amdgcn_sched_barrier(0);
    {
        const unsigned short* S0a = &lds[0][0][0];
        const unsigned short* S0b = &lds[0][1][0];
#pragma unroll
        for (int n = 0; n < 4; ++n) fb4[0][n] = LDF32(S0b, rb + n * 16);
#pragma unroll
        for (int m = 0; m < 4; ++m) falo[0][m] = LDF32(S0a, ra + m * 16);
    }

#define GBODY(p)                                                              \
    {                                                                         \
        const int kt = kt2 + (p);                                             \
        const unsigned short* Sc = &lds[kt & 3][0][0];                        \
        /* A-hi JIT reads of CURRENT tile: latency drains during barrier */   \
        bf16x8 h0 = LDF32(Sc, ra + 64);                                       \
        bf16x8 h1 = LDF32(Sc, ra + 80);                                       \
        bf16x8 h2 = LDF32(Sc, ra + 96);                                       \
        bf16x8 h3 = LDF32(Sc, ra + 112);                                      \
        if (kt + 2 < NT)                                                      \
            asm volatile("s_waitcnt vmcnt(4)" ::: "memory");                  \
        else if (kt + 1 < NT)                                                 \
            asm volatile("s_waitcnt vmcnt(0)" ::: "memory");                  \
        __builtin_amdgcn_s_barrier();                                         \
        __builtin_amdgcn_sched_barrier(0);                                    \
        __builtin_amdgcn_s_setprio(1);                                        \
        if (kt + 3 < NT) {                                                    \
            stage32(A, &lds[(kt + 3) & 3][0][0], tid, tileM, K,               \
                    (kt + 3) << 5);                                           \
            stage32(B, &lds[(kt + 3) & 3][1][0], tid, tileN, K,               \
                    (kt + 3) << 5);                                           \
        }                                                                     \
        if (kt + 1 < NT) {                                                    \
            const unsigned short* Na = &lds[(kt + 1) & 3][0][0];              \
            const unsigned short* Nb = &lds[(kt + 1) & 3][1][0];              \
            fb4[(p) ^ 1][0] = LDF32(Nb, rb + 0);                              \
            fb4[(p) ^ 1][1] = LDF32(Nb, rb + 16);                             \
            fb4[(p) ^ 1][2] = LDF32(Nb, rb + 32);                             \
            fb4[(p) ^ 1][3] = LDF32(Nb, rb + 48);                             \
            falo[(p) ^ 1][0] = LDF32(Na, ra + 0);                             \
            falo[(p) ^ 1][1] = LDF32(Na, ra + 16);                            \
            falo[(p) ^ 1][2] = LDF32(Na, ra + 32);                            \
            falo[(p) ^ 1][3] = LDF32(Na, ra + 48);                            \
        }                                                                     \
        _Pragma("unroll") for (int n = 0; n < 4; ++n) {                       \
            acc[0][n] = MFMA(falo[p][0], fb4[p][n], acc[0][n]);               \
            acc[1][n] = MFMA(falo[p][1], fb4[p][n], acc[1][n]);               \
            acc[2][n] = MFMA(falo[p][2], fb4[p][n], acc[2][n]);               \
            acc[3][n] = MFMA(falo[p][3], fb4[p][n], acc[3][n]);               \
        }                                                                     \
        _Pragma("unroll") for (int n = 0; n < 4; ++n) {                       \
            acc[4][n] = MFMA(h0, fb4[p][n], acc[4][n]);                       \
            acc[5][n] = MFMA(h1, fb4[p][n], acc[5][n]);                       \
            acc[6][n] = MFMA(h2, fb4[p][n], acc[6][n]);                       \
            acc[7][n] = MFMA(h3, fb4[p][n], acc[7][n]);                       \
        }                                                                     \
        __builtin_amdgcn_s_setprio(0);                                        \
    }

#pragma unroll 1
    for (int kt2 = 0; kt2 < NT; kt2 += 2) {
        GBODY(0)
        GBODY(1)
    }

    // ---- epilogue: C/D layout col = lane&15, row = (lane>>4)*4 + reg ----
    const int c0 = tileN + wc * 64 + l15;
    const int r0 = tileM + wr * 128 + lh * 4;
#pragma unroll
    for (int m = 0; m < 8; ++m)
#pragma unroll
        for (int n = 0; n < 4; ++n)
#pragma unroll
            for (int r = 0; r < 4; ++r)
                C[(size_t)(r0 + m * 16 + r) * N + (c0 + n * 16)] =
                    acc[m][n][r];
}

// ---------------------------------------------------------------------------
extern "C" void kernel_launch(void* const* d_in, const int* in_sizes, int n_in,
                              void* d_out, int out_size, void* d_ws,
                              size_t ws_size, hipStream_t stream) {
    const float* x = (const float*)d_in[0];  // [B,S,IN]  f32
    const float* w = (const float*)d_in[1];  // [OUT,IN]  f32
    float* out = (float*)d_out;              // [B,S,OUT] f32

    const long long MK = (long long)in_sizes[0];
    const long long NK = (long long)in_sizes[1];
    const long long MN = (long long)out_size;
    const long long K =
        (long long)(sqrt((double)MK * (double)NK / (double)MN) + 0.5);
    const long long M = MK / K;  // 16384
    const long long N = NK / K;  // 2048

    unsigned short* qx = (unsigned short*)d_ws;  // M*K bf16
    unsigned short* qw = qx + MK;                // N*K bf16

    quant_fake_int8_kernel<<<(int)(MK / 1024), 256, 0, stream>>>(x, qx, MK);
    quant_fake_int8_kernel<<<(int)(NK / 1024), 256, 0, stream>>>(w, qw, NK);

    dim3 grid(512);  // (M/256)*(N/256) = 64*8
    gemm_bf16_pipe<<<grid, 512, 0, stream>>>(qx, qw, out, (int)M, (int)N,
                                             (int)K);
}